// Round 1
// baseline (1616.509 us; speedup 1.0000x reference)
//
#include <hip/hip_runtime.h>
#include <cstddef>

namespace {

constexpr int    Bn   = 8;
constexpr int    Cc   = 64;    // value channels
constexpr int    Cq   = 8;     // q/k channels
constexpr int    Ln   = 256;   // H == W
constexpr size_t HWn  = 65536; // H*W
constexpr size_t NPIX = (size_t)Bn * HWn; // 524288

// workspace layout (floats)
constexpr size_t WT_OFF = 0;                      // 80*64 packed weights (padded)
constexpr size_t QR_OFF = 8192;                   // NPIX*8
constexpr size_t KR_OFF = QR_OFF + NPIX * 8;      // NPIX*8
constexpr size_t VR_OFF = KR_OFF + NPIX * 8;      // NPIX*64
constexpr size_t HO_OFF = VR_OFF + NPIX * 64;     // NPIX*64
// total = 8192 + 2*4194304 + 2*33554432 floats = ~302 MB

} // namespace

// K0: pack weights transposed: wt[c*80 + o], o = [q0..7 | k0..7 | v0..63]
__global__ void pack_weights(const float* __restrict__ Wq,
                             const float* __restrict__ Wk,
                             const float* __restrict__ Wv,
                             float* __restrict__ wt) {
  int idx = blockIdx.x * 256 + threadIdx.x;
  if (idx >= 64 * 80) return;
  int c = idx / 80, o = idx % 80;
  float v;
  if (o < 8)       v = Wq[o * 64 + c];
  else if (o < 16) v = Wk[(o - 8) * 64 + c];
  else             v = Wv[(o - 16) * 64 + c];
  wt[idx] = v;
}

// K1: per-pixel 1x1 convs. pix = ((b*256 + h)*256 + w)
__global__ __launch_bounds__(256) void qkv_kernel(
    const float* __restrict__ x, const float* __restrict__ wt,
    const float* __restrict__ bq, const float* __restrict__ bk,
    const float* __restrict__ bv,
    float* __restrict__ qr, float* __restrict__ kr, float* __restrict__ vr) {
  size_t p = (size_t)blockIdx.x * 256 + threadIdx.x; // 0..524287
  int b = (int)(p >> 16);
  int rem = (int)(p & 65535);
  const float* xb = x + (size_t)b * 64 * HWn + rem;

  float accq[8], acck[8], accv[64];
#pragma unroll
  for (int o = 0; o < 8; ++o) { accq[o] = bq[o]; acck[o] = bk[o]; }
#pragma unroll
  for (int o = 0; o < 64; ++o) accv[o] = bv[o];

  for (int c = 0; c < 64; ++c) {
    float xv = xb[(size_t)c * HWn];
    const float* w = wt + c * 80; // wave-uniform -> s_load
#pragma unroll
    for (int o = 0; o < 8; ++o) accq[o] += w[o] * xv;
#pragma unroll
    for (int o = 0; o < 8; ++o) acck[o] += w[8 + o] * xv;
#pragma unroll
    for (int o = 0; o < 64; ++o) accv[o] += w[16 + o] * xv;
  }

  float* q = qr + p * 8;
  float* k = kr + p * 8;
#pragma unroll
  for (int o = 0; o < 8; ++o) { q[o] = accq[o]; k[o] = acck[o]; }
  float* v = vr + p * 64;
#pragma unroll
  for (int o = 0; o < 64; ++o) v[o] = accv[o];
}

// K2: generic criss-cross attention slice.
// S[i,j] = sum_c Q[c,i]K[c,j]; P = softmax_j(S); Out[c,j] = sum_i V[c,i]P[i,j]
// MODE 0 (row pass): slice = (b,h), i/j over w. Out -> d_out natural layout (w_out).
// MODE 1 (col pass): slice = (b,w), i/j over h. Out -> ho[b][w][c][h].
template <int MODE>
__global__ __launch_bounds__(256) void attn_kernel(
    const float* __restrict__ q, const float* __restrict__ k,
    const float* __restrict__ v, float* __restrict__ o) {
  const int s = blockIdx.x;  // 0..2047
  const int t = threadIdx.x; // 0..255
  const int b = s >> 8;
  const int r = s & 255; // h (row mode) or w (col mode)

  __shared__ float lds_m[Ln];
  __shared__ float lds_iz[Ln];

  const float* qbase;
  const float* kbase;
  const float* vbase;
  size_t qstride, vstride;
  if (MODE == 0) {
    qbase = q + (size_t)s * (Ln * Cq);
    kbase = k + (size_t)s * (Ln * Cq);
    vbase = v + (size_t)s * (Ln * Cc);
    qstride = Cq;
    vstride = Cc;
  } else {
    qbase = q + ((size_t)b * HWn + r) * Cq;
    kbase = k + ((size_t)b * HWn + r) * Cq;
    vbase = v + ((size_t)b * HWn + r) * Cc;
    qstride = (size_t)Ln * Cq;
    vstride = (size_t)Ln * Cc;
  }

  // ---- phase 1: this thread owns row i = t; compute m_i, 1/Z_i ----
  float qreg[Cq];
  {
    const float* qi = qbase + (size_t)t * qstride;
#pragma unroll
    for (int c = 0; c < Cq; ++c) qreg[c] = qi[c];
  }
  float mval = -3.0e38f;
  for (int j = 0; j < Ln; ++j) {
    const float* kj = kbase + (size_t)j * qstride; // uniform -> s_load
    float sd = 0.f;
#pragma unroll
    for (int c = 0; c < Cq; ++c) sd += qreg[c] * kj[c];
    mval = fmaxf(mval, sd);
  }
  float zval = 0.f;
  for (int j = 0; j < Ln; ++j) {
    const float* kj = kbase + (size_t)j * qstride;
    float sd = 0.f;
#pragma unroll
    for (int c = 0; c < Cq; ++c) sd += qreg[c] * kj[c];
    zval += __expf(sd - mval);
  }
  lds_m[t] = mval;
  lds_iz[t] = 1.0f / zval;
  __syncthreads();

  // ---- phase 2: this thread owns output column j = t ----
  float kreg[Cq];
  {
    const float* kj = kbase + (size_t)t * qstride;
#pragma unroll
    for (int c = 0; c < Cq; ++c) kreg[c] = kj[c];
  }
  float acc[Cc];
#pragma unroll
  for (int c = 0; c < Cc; ++c) acc[c] = 0.f;

  for (int i = 0; i < Ln; ++i) {
    const float* qi = qbase + (size_t)i * qstride; // uniform -> s_load
    float sd = 0.f;
#pragma unroll
    for (int c = 0; c < Cq; ++c) sd += qi[c] * kreg[c];
    const float p = __expf(sd - lds_m[i]) * lds_iz[i];
    const float* vi = vbase + (size_t)i * vstride; // uniform -> s_load
#pragma unroll
    for (int c = 0; c < Cc; ++c) acc[c] += vi[c] * p;
  }

  if (MODE == 0) {
    // w_out[b,c,h=r,w=t] -> d_out natural layout, coalesced over t
    float* ob = o + (size_t)b * (Cc * HWn) + (size_t)r * Ln + t;
#pragma unroll
    for (int c = 0; c < Cc; ++c) ob[(size_t)c * HWn] = acc[c];
  } else {
    // ho[b][w=r][c][h=t], coalesced over t
    float* ob = o + (size_t)s * (Ln * Cc) + t;
#pragma unroll
    for (int c = 0; c < Cc; ++c) ob[(size_t)c * Ln] = acc[c];
  }
}

// K3: out = gamma*(w_out(in d_out) + h_out(transposed from ho)) + x
// block: (h-strip of 16) x c x b ; LDS-tiled transpose of ho
__global__ __launch_bounds__(256) void merge_kernel(
    const float* __restrict__ wout, const float* __restrict__ ho,
    const float* __restrict__ x, const float* __restrict__ gamma,
    float* __restrict__ out) {
  const int h0 = blockIdx.x * 16;
  const int c = blockIdx.y;
  const int b = blockIdx.z;
  const int t = threadIdx.x;
  __shared__ float lds[256 * 17]; // [w][hh] padded

  const float g = gamma[0];

#pragma unroll
  for (int it = 0; it < 16; ++it) {
    int e = it * 256 + t;
    int w = e >> 4, hh = e & 15;
    lds[w * 17 + hh] = ho[(((size_t)b * 256 + w) * 64 + c) * 256 + h0 + hh];
  }
  __syncthreads();

#pragma unroll
  for (int rr = 0; rr < 16; ++rr) {
    size_t idx = (((size_t)b * 64 + c) * 256 + h0 + rr) * 256 + t;
    out[idx] = g * (wout[idx] + lds[t * 17 + rr]) + x[idx];
  }
}

extern "C" void kernel_launch(void* const* d_in, const int* in_sizes, int n_in,
                              void* d_out, int out_size, void* d_ws, size_t ws_size,
                              hipStream_t stream) {
  const float* x     = (const float*)d_in[0];
  const float* Wq    = (const float*)d_in[1];
  const float* bq    = (const float*)d_in[2];
  const float* Wk    = (const float*)d_in[3];
  const float* bk    = (const float*)d_in[4];
  const float* Wv    = (const float*)d_in[5];
  const float* bv    = (const float*)d_in[6];
  const float* gamma = (const float*)d_in[7];
  float* out = (float*)d_out;
  float* ws  = (float*)d_ws;

  float* wt = ws + WT_OFF;
  float* qr = ws + QR_OFF;
  float* kr = ws + KR_OFF;
  float* vr = ws + VR_OFF;
  float* ho = ws + HO_OFF;

  hipLaunchKernelGGL(pack_weights, dim3(20), dim3(256), 0, stream, Wq, Wk, Wv, wt);
  hipLaunchKernelGGL(qkv_kernel, dim3(2048), dim3(256), 0, stream,
                     x, wt, bq, bk, bv, qr, kr, vr);
  hipLaunchKernelGGL((attn_kernel<0>), dim3(2048), dim3(256), 0, stream,
                     qr, kr, vr, out); // row pass -> w_out in d_out
  hipLaunchKernelGGL((attn_kernel<1>), dim3(2048), dim3(256), 0, stream,
                     qr, kr, vr, ho);  // col pass -> h_out in ws
  hipLaunchKernelGGL(merge_kernel, dim3(16, 64, 8), dim3(256), 0, stream,
                     out, ho, x, gamma, out);
}